// Round 8
// baseline (167.361 us; speedup 1.0000x reference)
//
#include <hip/hip_runtime.h>
#include <hip/hip_bf16.h>

#define BB 8
#define LL 4096
#define NCH 8192
#define IDIM 256
#define KDIM 512
#define ODIM 512
#define NDIR 6
#define TOT (BB * LL)  // 32768

// Per-dir fixed-capacity buckets (expected ~5461/dir; 8192 = huge headroom).
#define CAP 8192
#define IDX_OFF 64
#define ROWS_OFF (64 + 8 * CAP)
#define WS_LAST_OFF (64 + 16 * CAP)
#define LAST_ELEMS (BB * NCH * IDIM)  // 16,777,216
#define W_ELEMS (NDIR * ODIM * KDIM)  // 1,572,864
#define N_LAST8 (LAST_ELEMS / 8)      // 2,097,152 -> 8192 blocks
#define N_W8 (W_ELEMS / 8)            // 196,608  -> 768 blocks

// gemm grid: 2 n-tiles x 262 m-tiles = 524 blocks (bijective XCD swizzle,
// 524 = 8*65 + 4 -> q=65, r=4 chunked mapping).
#define NWG 524

typedef short short8 __attribute__((ext_vector_type(8)));
typedef float floatx4 __attribute__((ext_vector_type(4)));

__device__ inline void async_copy16(const void* g, void* l) {
  __builtin_amdgcn_global_load_lds(
      (const __attribute__((address_space(1))) void*)g,
      (__attribute__((address_space(3))) void*)l, 16, 0, 0);
}

__device__ inline void cvt8(const float* __restrict__ src,
                            __hip_bfloat16* __restrict__ dst, int i) {
  const floatx4* s = (const floatx4*)src;
  floatx4 a = s[2 * i];
  floatx4 b = s[2 * i + 1];
  union { short8 v; __hip_bfloat16 h[8]; } u;
  u.h[0] = __float2bfloat16(a[0]); u.h[1] = __float2bfloat16(a[1]);
  u.h[2] = __float2bfloat16(a[2]); u.h[3] = __float2bfloat16(a[3]);
  u.h[4] = __float2bfloat16(b[0]); u.h[5] = __float2bfloat16(b[1]);
  u.h[6] = __float2bfloat16(b[2]); u.h[7] = __float2bfloat16(b[3]);
  ((short8*)dst)[i] = u.v;
}

// ---- prep: cvt(last) + cvt(W) + scatter into fixed-cap buckets, fused ----
__global__ __launch_bounds__(256) void prep_kernel(
    const float* __restrict__ last, const float* __restrict__ W,
    const int* __restrict__ vec, const int* __restrict__ child_l,
    const int* __restrict__ child_r, const int* __restrict__ drev,
    const int* __restrict__ dmap, int* __restrict__ ws) {
  __hip_bfloat16* last_bf = (__hip_bfloat16*)(ws + WS_LAST_OFF);
  __hip_bfloat16* W_bf = last_bf + LAST_ELEMS;
  int gid = blockIdx.x * 256 + threadIdx.x;
  if (gid < N_LAST8) {
    cvt8(last, last_bf, gid);
  } else if (gid < N_LAST8 + N_W8) {
    cvt8(W, W_bf, gid - N_LAST8);
  } else {
    __shared__ int lcnt[8];
    __shared__ int gbase[8];
    int tid = threadIdx.x;
    if (tid < 8) lcnt[tid] = 0;
    __syncthreads();
    int lin = gid - (N_LAST8 + N_W8);
    int l = lin & (LL - 1);
    int v = vec[lin];
    int dir = dmap[v] & 7;
    int sw = drev[v];
    int cl = child_l[l];
    int cr = child_r[l];
    int r0 = sw ? cr : cl;
    int r1 = sw ? cl : cr;
    int pos = atomicAdd(&lcnt[dir], 1);
    __syncthreads();
    if (tid < 8) gbase[tid] = lcnt[tid] ? atomicAdd(&ws[tid], lcnt[tid]) : 0;
    __syncthreads();
    int slot = dir * CAP + gbase[dir] + pos;
    ws[IDX_OFF + slot] = lin;
    ws[ROWS_OFF + slot] = r0 | (r1 << 16);
  }
}

// ---- grouped GEMM: 128M x 256N tile, BK=32, deep pipeline ----
// 4 waves (2m x 2n), each wave 64x128 via 4x8 mfma_f32_16x16x32_bf16 (32
// MFMA per wave per step -> 2x R7's per-barrier work at 1.5x the staging).
// A: 3 x 8KB buffers (2 ahead, covers gather latency). B: 2 x 16KB (1 ahead,
// L2-hot W copy). LDS 56KB -> 2 blocks/CU (acc=128 AGPR caps at 2 anyway).
// Counted vmcnt(8): pipeline never drains in the main loop.
// LDS layout (both A and B, proven 0-conflict in R6/R7): row-PAIRS packed
// into 128B lines; 16B-unit u' = 4*(row&1)+k16 stored at u = u' ^ (line&7);
// lane-linear LDS dest, inverse permutation on the global source address.
__global__ __launch_bounds__(256, 2) void gemm_kernel(
    const float* __restrict__ bias, const float* __restrict__ alpha_m,
    const int* __restrict__ ws, float* __restrict__ out) {
  __shared__ __hip_bfloat16 Als[3][128 * 32];  // 24 KB
  __shared__ __hip_bfloat16 Bls[2][256 * 32];  // 32 KB

  // bijective XCD swizzle (nwg=524, q=65, r=4): each XCD gets a contiguous
  // swz chunk -> contiguous m-tiles incl. both n-tiles (A shared in its L2).
  int flat = blockIdx.x;
  int xcd = flat & 7;
  int swz = (xcd < 4 ? xcd * 66 : 264 + (xcd - 4) * 65) + (flat >> 3);
  const int mt = swz >> 1;
  const int nt = swz & 1;

  // ---- tile -> dir mapping (counts = fill cursors at ws[0..7]) ----
  int d = -1, count = 0, m_base = 0;
  {
    int tb = 0;
    for (int dd = 0; dd < 8; ++dd) {
      int c = ws[dd];
      int ntile = (c + 127) >> 7;
      if (mt < tb + ntile) { d = dd; count = c; m_base = (mt - tb) * 128; break; }
      tb += ntile;
    }
  }
  if (d < 0) return;

  const int* idxA = ws + IDX_OFF + d * CAP;
  const int* rowsA = ws + ROWS_OFF + d * CAP;
  const __hip_bfloat16* last_bf = (const __hip_bfloat16*)(ws + WS_LAST_OFF);
  const __hip_bfloat16* W_bf = last_bf + LAST_ELEMS;

  const int tid = threadIdx.x;
  const int wave = __builtin_amdgcn_readfirstlane(tid >> 6);
  const int lane = tid & 63;
  const int lane15 = lane & 15;
  const int quad = lane >> 4;
  const int wm = wave >> 1;  // 0..1 : 64-row half
  const int wn = wave & 1;   // 0..1 : 128-col half
  const int n_blk = nt * 256;

  // ---- staging descriptors (row-pair packed 128B lines) ----
  // lane l: lp = l>>3 (line in instr), u' = (l&7)^lp; row = I*16+2*lp+(u'>>2),
  // k16 = u'&3 (16B unit within the row's 64B chunk).
  const __hip_bfloat16* ap0[2];
  const __hip_bfloat16* ap1[2];
  const __hip_bfloat16* bp[4];
  int ldsA[2], ldsB[4];
  {
    const int lp = lane >> 3;
    const int up = (lane & 7) ^ lp;
    const int k16e = (up & 3) * 8;  // elem offset within 64B chunk
#pragma unroll
    for (int i = 0; i < 2; ++i) {  // A: 2 instrs/wave, 16 rows each (128 rows)
      const int I = wave * 2 + i;
      ldsA[i] = I * 512;  // 1 KB per instr
      int row_local = I * 16 + 2 * lp + (up >> 2);
      int gr = m_base + row_local;
      if (gr >= count) gr = count - 1;  // clamp (tile exists => count>0)
      int lin = idxA[gr] & (TOT - 1);
      int rr = rowsA[gr];
      int b = lin >> 12;
      ap0[i] = last_bf + (long long)(b * NCH + (rr & (NCH - 1))) * IDIM + k16e;
      ap1[i] = last_bf + (long long)(b * NCH + ((rr >> 16) & (NCH - 1))) * IDIM + k16e;
    }
#pragma unroll
    for (int i = 0; i < 4; ++i) {  // B: 4 instrs/wave, 16 rows each (256 rows)
      const int I = wave * 4 + i;
      ldsB[i] = I * 512;
      int row_local = I * 16 + 2 * lp + (up >> 2);
      bp[i] = W_bf + (long long)(d * ODIM + n_blk + row_local) * KDIM + k16e;
    }
  }

#define STAGE_A(c, buf)                                               \
  {                                                                   \
    const int ko = ((c) & 7) * 32;                                    \
    _Pragma("unroll") for (int i = 0; i < 2; ++i)                     \
        async_copy16(((c) < 8 ? ap0[i] : ap1[i]) + ko,                \
                     &Als[(buf)][ldsA[i]]);                           \
  }
#define STAGE_B(c, buf)                                               \
  {                                                                   \
    _Pragma("unroll") for (int i = 0; i < 4; ++i)                     \
        async_copy16(bp[i] + (c) * 32, &Bls[(buf)][ldsB[i]]);         \
  }

  floatx4 acc[4][8] = {};
  // frag-read: row r -> line r>>1; unit u = (4*(r&1)+quad)^((r>>1)&7)
  const int t3 = lane15 >> 1;
  const int col8 = (((lane15 & 1) * 4 + quad) ^ t3) * 8;

  // prologue (oldest-first for FIFO vmcnt): B(0), A(0), A(1)
  STAGE_B(0, 0);
  STAGE_A(0, 0);
  STAGE_A(1, 1);

#pragma unroll
  for (int c = 0; c < 16; ++c) {
    // barrier 1: all waves done reading the buffers about to be overwritten
    __builtin_amdgcn_s_barrier();
    if (c < 15) STAGE_B(c + 1, (c + 1) & 1);
    if (c < 14) STAGE_A(c + 2, (c + 2) % 3);
    // FIFO stream: ..., A(c)2, B(c)4, A(c+1)2, B(c+1)4, A(c+2)2
    // need A(c),B(c) done -> 8 newer ops may remain in flight.
    if (c < 14) {
      asm volatile("s_waitcnt vmcnt(8)" ::: "memory");
    } else if (c == 14) {
      asm volatile("s_waitcnt vmcnt(6)" ::: "memory");  // A(15)2+B(15)4 remain
    } else {
      asm volatile("s_waitcnt vmcnt(0)" ::: "memory");
    }
    __builtin_amdgcn_sched_barrier(0);
    // barrier 2: every wave's stage(c) visible to all
    __builtin_amdgcn_s_barrier();

    const __hip_bfloat16* Ab = Als[c % 3];
    const __hip_bfloat16* Bb = Bls[c & 1];
    short8 a[4];
#pragma unroll
    for (int i = 0; i < 4; ++i)
      a[i] = *(const short8*)&Ab[(wm * 32 + i * 8 + t3) * 64 + col8];
#pragma unroll
    for (int jg = 0; jg < 2; ++jg) {  // two groups of 4 B-frags (reg liveness)
      short8 b[4];
#pragma unroll
      for (int j = 0; j < 4; ++j)
        b[j] = *(const short8*)&Bb[(wn * 64 + (jg * 4 + j) * 8 + t3) * 64 + col8];
#pragma unroll
      for (int i = 0; i < 4; ++i)
#pragma unroll
        for (int j = 0; j < 4; ++j)
          acc[i][jg * 4 + j] =
              __builtin_amdgcn_mfma_f32_16x16x32_bf16(a[i], b[j], acc[i][jg * 4 + j], 0, 0, 0);
    }
  }

  // ---- epilogue: bias + leaky relu, scatter rows ----
  const float alpha = alpha_m[d];
  float bj[8];
#pragma unroll
  for (int j = 0; j < 8; ++j)
    bj[j] = bias[d * ODIM + n_blk + wn * 128 + j * 16 + lane15];

#pragma unroll
  for (int i = 0; i < 4; ++i) {
#pragma unroll
    for (int reg = 0; reg < 4; ++reg) {
      int row_id = m_base + wm * 64 + i * 16 + quad * 4 + reg;
      if (row_id >= count) continue;
      int lin = idxA[row_id] & (TOT - 1);
      float* orow = out + (long long)lin * ODIM + n_blk + wn * 128;
#pragma unroll
      for (int j = 0; j < 8; ++j) {
        float y = acc[i][j][reg] + bj[j];
        y = y > 0.f ? y : alpha * y;
        orow[j * 16 + lane15] = y;
      }
    }
  }
}

extern "C" void kernel_launch(void* const* d_in, const int* in_sizes, int n_in,
                              void* d_out, int out_size, void* d_ws, size_t ws_size,
                              hipStream_t stream) {
  const float* last = (const float*)d_in[0];
  const float* W = (const float*)d_in[1];
  const float* bias = (const float*)d_in[2];
  const float* alpha = (const float*)d_in[3];
  const int* child_l = (const int*)d_in[4];
  const int* child_r = (const int*)d_in[5];
  const int* vec = (const int*)d_in[6];
  const int* drev = (const int*)d_in[7];
  const int* dmap = (const int*)d_in[8];

  int* ws = (int*)d_ws;

  hipMemsetAsync(ws, 0, 64 * sizeof(int), stream);
  // fused prep: last-cvt (8192 blocks) + W-cvt (768) + scatter (128)
  int prep_blocks = N_LAST8 / 256 + N_W8 / 256 + TOT / 256;
  prep_kernel<<<prep_blocks, 256, 0, stream>>>(last, W, vec, child_l, child_r,
                                               drev, dmap, ws);
  gemm_kernel<<<NWG, 256, 0, stream>>>(bias, alpha, ws, (float*)d_out);
}